// Round 1
// baseline (926.575 us; speedup 1.0000x reference)
//
#include <hip/hip_runtime.h>

// Texture pyramid bilinear sampling.
// Reference: out[b, c, h, w] = sum_{lvl=1..4} grid_sample(p1_lvl, gx, gy)
// for all c in {0,1,2} (pyramid1 is sampled three times -> identical channels).
// gx = x[...,0]*2-1, gy = x[...,1]*2-1; align_corners=False, zero padding.

template <int N>
__device__ __forceinline__ float sample_level(const float* __restrict__ t,
                                              float gx, float gy) {
    // unnormalize (align_corners=False): ix = ((gx+1)*N - 1) * 0.5
    float ix = ((gx + 1.0f) * (float)N - 1.0f) * 0.5f;
    float iy = ((gy + 1.0f) * (float)N - 1.0f) * 0.5f;
    float x0f = floorf(ix);
    float y0f = floorf(iy);
    float wx1 = ix - x0f;
    float wy1 = iy - y0f;
    float wx0 = 1.0f - wx1;
    float wy0 = 1.0f - wy1;
    int x0 = (int)x0f;
    int y0 = (int)y0f;
    // validity per corner (zero padding outside [0, N-1])
    bool vx0 = (x0 >= 0) & (x0 <= N - 1);
    bool vx1 = (x0 >= -1) & (x0 <= N - 2);
    bool vy0 = (y0 >= 0) & (y0 <= N - 1);
    bool vy1 = (y0 >= -1) & (y0 <= N - 2);
    // clamped indices (always in-bounds loads, select 0 when invalid)
    int x0c = min(max(x0, 0), N - 1);
    int x1c = min(max(x0 + 1, 0), N - 1);
    int y0c = min(max(y0, 0), N - 1);
    int y1c = min(max(y0 + 1, 0), N - 1);
    const float* r0 = t + y0c * N;
    const float* r1 = t + y1c * N;
    float v00 = (vx0 & vy0) ? r0[x0c] : 0.0f;
    float v10 = (vx1 & vy0) ? r0[x1c] : 0.0f;
    float v01 = (vx0 & vy1) ? r1[x0c] : 0.0f;
    float v11 = (vx1 & vy1) ? r1[x1c] : 0.0f;
    return wx0 * wy0 * v00 + wx1 * wy0 * v10 + wx0 * wy1 * v01 + wx1 * wy1 * v11;
}

__global__ __launch_bounds__(256) void texture_pyramid_kernel(
    const float2* __restrict__ x,   // [B*HO*WO] of (gx_raw, gy_raw) in [0,1]
    const float* __restrict__ l1,   // [1024,1024]
    const float* __restrict__ l2,   // [512,512]
    const float* __restrict__ l3,   // [256,256]
    const float* __restrict__ l4,   // [128,128]
    float* __restrict__ out)        // [B, 3, HO, WO]
{
    const int p = blockIdx.x * 256 + threadIdx.x;  // pixel index, < 16 * 2^20
    float2 g = x[p];
    float gx = g.x * 2.0f - 1.0f;
    float gy = g.y * 2.0f - 1.0f;

    float y = sample_level<1024>(l1, gx, gy)
            + sample_level<512>(l2, gx, gy)
            + sample_level<256>(l3, gx, gy)
            + sample_level<128>(l4, gx, gy);

    const int b   = p >> 20;            // HO*WO = 2^20
    const int rem = p & ((1 << 20) - 1);
    float* o = out + ((size_t)(b * 3) << 20) + rem;
    o[0]                = y;
    o[(size_t)1 << 20]  = y;
    o[(size_t)2 << 20]  = y;
}

extern "C" void kernel_launch(void* const* d_in, const int* in_sizes, int n_in,
                              void* d_out, int out_size, void* d_ws, size_t ws_size,
                              hipStream_t stream) {
    const float2* x  = (const float2*)d_in[0];
    const float*  l1 = (const float*)d_in[1];
    const float*  l2 = (const float*)d_in[2];
    const float*  l3 = (const float*)d_in[3];
    const float*  l4 = (const float*)d_in[4];
    float* out = (float*)d_out;

    const int total_pixels = 16 * 1024 * 1024;   // B * HO * WO = 2^24
    const int block = 256;
    const int grid = total_pixels / block;       // 65536
    texture_pyramid_kernel<<<grid, block, 0, stream>>>(x, l1, l2, l3, l4, out);
}

// Round 2
// 425.992 us; speedup vs baseline: 2.1751x; 2.1751x over previous
//
#include <hip/hip_runtime.h>

// Texture pyramid bilinear sampling (see reference): all 3 output channels are
// the SAME pyramid1 sum -> compute once, write 3 planes.
//
// Strategy: pre-pack each pyramid level into a (N+1)x(N+1) "quad" texture of
// bf16x4 (uint2): entry (y0+1, x0+1) = { t[y0][x0], t[y0][x0+1],
//                                        t[y0+1][x0], t[y0+1][x0+1] }
// with zero border (implements zero-padding; x in [0,1] => x0 in [-1, N-1]).
// Bilinear sample of one level = ONE scattered 8B load instead of four 4B
// loads -> 4x fewer divergent memory transactions (the measured bottleneck).

__device__ __forceinline__ unsigned bf16_rne(float f) {
    unsigned u = __float_as_uint(f);
    return (u + 0x7fffu + ((u >> 16) & 1u)) >> 16;
}

template <int N>
__global__ __launch_bounds__(256) void pack_kernel(const float* __restrict__ t,
                                                   uint2* __restrict__ q) {
    const int idx = blockIdx.x * 256 + threadIdx.x;
    constexpr int NP1 = N + 1;
    if (idx >= NP1 * NP1) return;
    const int ey = idx / NP1;
    const int ex = idx - ey * NP1;
    const int y0 = ey - 1, x0 = ex - 1;
    const bool yv0 = (unsigned)y0 < (unsigned)N;
    const bool yv1 = (unsigned)(y0 + 1) < (unsigned)N;
    const bool xv0 = (unsigned)x0 < (unsigned)N;
    const bool xv1 = (unsigned)(x0 + 1) < (unsigned)N;
    const float v00 = (yv0 & xv0) ? t[y0 * N + x0] : 0.0f;
    const float v10 = (yv0 & xv1) ? t[y0 * N + x0 + 1] : 0.0f;
    const float v01 = (yv1 & xv0) ? t[(y0 + 1) * N + x0] : 0.0f;
    const float v11 = (yv1 & xv1) ? t[(y0 + 1) * N + x0 + 1] : 0.0f;
    uint2 r;
    r.x = bf16_rne(v00) | (bf16_rne(v10) << 16);
    r.y = bf16_rne(v01) | (bf16_rne(v11) << 16);
    q[idx] = r;
}

template <int N>
__device__ __forceinline__ float sample_packed(const uint2* __restrict__ q,
                                               float u, float v) {
    // u, v are the RAW inputs in [0,1]; ix = ((2u-1+1)*N - 1)/2 = u*N - 0.5
    float ix = fmaf(u, (float)N, -0.5f);
    float iy = fmaf(v, (float)N, -0.5f);
    float x0f = floorf(ix);
    float y0f = floorf(iy);
    float wx1 = ix - x0f;
    float wy1 = iy - y0f;
    int ex = (int)x0f + 1;
    int ey = (int)y0f + 1;
    ex = min(max(ex, 0), N);   // safety clamp (inputs in [0,1] keep this a no-op)
    ey = min(max(ey, 0), N);
    uint2 p = q[ey * (N + 1) + ex];
    float v00 = __uint_as_float(p.x << 16);
    float v10 = __uint_as_float(p.x & 0xffff0000u);
    float v01 = __uint_as_float(p.y << 16);
    float v11 = __uint_as_float(p.y & 0xffff0000u);
    float wx0 = 1.0f - wx1;
    float wy0 = 1.0f - wy1;
    float r0 = fmaf(wx0, v00, wx1 * v10);
    float r1 = fmaf(wx0, v01, wx1 * v11);
    return fmaf(wy0, r0, wy1 * r1);
}

__global__ __launch_bounds__(256) void texture_quad_kernel(
    const float2* __restrict__ x,
    const uint2* __restrict__ q1,   // (1025)^2
    const uint2* __restrict__ q2,   // (513)^2
    const uint2* __restrict__ q3,   // (257)^2
    const uint2* __restrict__ q4,   // (129)^2
    float* __restrict__ out)
{
    const int p = blockIdx.x * 256 + threadIdx.x;
    float2 g = x[p];

    float y = sample_packed<1024>(q1, g.x, g.y)
            + sample_packed<512>(q2, g.x, g.y)
            + sample_packed<256>(q3, g.x, g.y)
            + sample_packed<128>(q4, g.x, g.y);

    const int b   = p >> 20;
    const int rem = p & ((1 << 20) - 1);
    float* o = out + ((size_t)(b * 3) << 20) + rem;
    o[0]               = y;
    o[(size_t)1 << 20] = y;
    o[(size_t)2 << 20] = y;
}

// ---------- fallback (round-1 direct kernel, used only if d_ws too small) ----
template <int N>
__device__ __forceinline__ float sample_level(const float* __restrict__ t,
                                              float gx, float gy) {
    float ix = ((gx + 1.0f) * (float)N - 1.0f) * 0.5f;
    float iy = ((gy + 1.0f) * (float)N - 1.0f) * 0.5f;
    float x0f = floorf(ix), y0f = floorf(iy);
    float wx1 = ix - x0f, wy1 = iy - y0f;
    float wx0 = 1.0f - wx1, wy0 = 1.0f - wy1;
    int x0 = (int)x0f, y0 = (int)y0f;
    bool vx0 = (x0 >= 0) & (x0 <= N - 1);
    bool vx1 = (x0 >= -1) & (x0 <= N - 2);
    bool vy0 = (y0 >= 0) & (y0 <= N - 1);
    bool vy1 = (y0 >= -1) & (y0 <= N - 2);
    int x0c = min(max(x0, 0), N - 1), x1c = min(max(x0 + 1, 0), N - 1);
    int y0c = min(max(y0, 0), N - 1), y1c = min(max(y0 + 1, 0), N - 1);
    const float* r0 = t + y0c * N;
    const float* r1 = t + y1c * N;
    float v00 = (vx0 & vy0) ? r0[x0c] : 0.0f;
    float v10 = (vx1 & vy0) ? r0[x1c] : 0.0f;
    float v01 = (vx0 & vy1) ? r1[x0c] : 0.0f;
    float v11 = (vx1 & vy1) ? r1[x1c] : 0.0f;
    return wx0 * wy0 * v00 + wx1 * wy0 * v10 + wx0 * wy1 * v01 + wx1 * wy1 * v11;
}

__global__ __launch_bounds__(256) void texture_pyramid_kernel(
    const float2* __restrict__ x,
    const float* __restrict__ l1, const float* __restrict__ l2,
    const float* __restrict__ l3, const float* __restrict__ l4,
    float* __restrict__ out)
{
    const int p = blockIdx.x * 256 + threadIdx.x;
    float2 g = x[p];
    float gx = g.x * 2.0f - 1.0f;
    float gy = g.y * 2.0f - 1.0f;
    float y = sample_level<1024>(l1, gx, gy) + sample_level<512>(l2, gx, gy)
            + sample_level<256>(l3, gx, gy) + sample_level<128>(l4, gx, gy);
    const int b = p >> 20;
    const int rem = p & ((1 << 20) - 1);
    float* o = out + ((size_t)(b * 3) << 20) + rem;
    o[0] = y; o[(size_t)1 << 20] = y; o[(size_t)2 << 20] = y;
}
// ----------------------------------------------------------------------------

extern "C" void kernel_launch(void* const* d_in, const int* in_sizes, int n_in,
                              void* d_out, int out_size, void* d_ws, size_t ws_size,
                              hipStream_t stream) {
    const float2* x  = (const float2*)d_in[0];
    const float*  l1 = (const float*)d_in[1];
    const float*  l2 = (const float*)d_in[2];
    const float*  l3 = (const float*)d_in[3];
    const float*  l4 = (const float*)d_in[4];
    float* out = (float*)d_out;

    const int total_pixels = 16 * 1024 * 1024;
    const int block = 256;
    const int grid = total_pixels / block;

    // packed-quad workspace layout (bytes)
    const size_t n1 = 1025ull * 1025ull, n2 = 513ull * 513ull,
                 n3 = 257ull * 257ull,   n4 = 129ull * 129ull;
    const size_t need = (n1 + n2 + n3 + n4) * sizeof(uint2);

    if (ws_size >= need) {
        uint2* q1 = (uint2*)d_ws;
        uint2* q2 = q1 + n1;
        uint2* q3 = q2 + n2;
        uint2* q4 = q3 + n3;
        pack_kernel<1024><<<(int)((n1 + 255) / 256), 256, 0, stream>>>(l1, q1);
        pack_kernel< 512><<<(int)((n2 + 255) / 256), 256, 0, stream>>>(l2, q2);
        pack_kernel< 256><<<(int)((n3 + 255) / 256), 256, 0, stream>>>(l3, q3);
        pack_kernel< 128><<<(int)((n4 + 255) / 256), 256, 0, stream>>>(l4, q4);
        texture_quad_kernel<<<grid, block, 0, stream>>>(x, q1, q2, q3, q4, out);
    } else {
        texture_pyramid_kernel<<<grid, block, 0, stream>>>(x, l1, l2, l3, l4, out);
    }
}

// Round 3
// 351.624 us; speedup vs baseline: 2.6351x; 1.2115x over previous
//
#include <hip/hip_runtime.h>
#include <hip/hip_fp16.h>

// Texture pyramid bilinear sampling. All 3 output channels are the SAME
// pyramid1 sum -> compute once, write 3 planes.
//
// Round-3 strategy: the sum of the 4 levels' bilinear samples is piecewise
// bilinear on a single 2048^2 cell grid (each level's breakpoints lie at
// multiples of 1/2048, and a sum of bilinear forms is bilinear per cell;
// grid_sample is continuous). So:
//   1) build_nodes: evaluate F at the 2049^2 grid nodes (coalesced, exact)
//      and scatter each node value (fp16) into the 4 quad slots it belongs to.
//   2) main kernel: ONE scattered 8B quad load per pixel + one bilinear lerp.
// This takes the measured bottleneck (scattered lane-miss rate in the L1/TA
// pipe, ~4 cyc/miss-lane) from 4 misses/pixel to 1.

// ---------- shared: round-1 exact f32 sampler (validity = zero padding) -----
template <int N>
__device__ __forceinline__ float sample_level(const float* __restrict__ t,
                                              float gx, float gy) {
    float ix = ((gx + 1.0f) * (float)N - 1.0f) * 0.5f;
    float iy = ((gy + 1.0f) * (float)N - 1.0f) * 0.5f;
    float x0f = floorf(ix), y0f = floorf(iy);
    float wx1 = ix - x0f, wy1 = iy - y0f;
    float wx0 = 1.0f - wx1, wy0 = 1.0f - wy1;
    int x0 = (int)x0f, y0 = (int)y0f;
    bool vx0 = (x0 >= 0) & (x0 <= N - 1);
    bool vx1 = (x0 >= -1) & (x0 <= N - 2);
    bool vy0 = (y0 >= 0) & (y0 <= N - 1);
    bool vy1 = (y0 >= -1) & (y0 <= N - 2);
    int x0c = min(max(x0, 0), N - 1), x1c = min(max(x0 + 1, 0), N - 1);
    int y0c = min(max(y0, 0), N - 1), y1c = min(max(y0 + 1, 0), N - 1);
    const float* r0 = t + y0c * N;
    const float* r1 = t + y1c * N;
    float v00 = (vx0 & vy0) ? r0[x0c] : 0.0f;
    float v10 = (vx1 & vy0) ? r0[x1c] : 0.0f;
    float v01 = (vx0 & vy1) ? r1[x0c] : 0.0f;
    float v11 = (vx1 & vy1) ? r1[x1c] : 0.0f;
    return wx0 * wy0 * v00 + wx1 * wy0 * v10 + wx0 * wy1 * v01 + wx1 * wy1 * v11;
}

// ---------- round-3: supertexture build + sample ----------------------------
// Node (i,j), i,j in [0,2048]: u=i/2048, v=j/2048 (gx=(i-1024)/1024 exact).
// Quad entry (j0,i0), 2048^2, 4 ushort slots: {n(i0,j0), n(i0+1,j0),
//                                              n(i0,j0+1), n(i0+1,j0+1)}.
__global__ __launch_bounds__(256) void build_nodes_kernel(
    const float* __restrict__ l1, const float* __restrict__ l2,
    const float* __restrict__ l3, const float* __restrict__ l4,
    unsigned short* __restrict__ Qs)
{
    const int idx = blockIdx.x * 256 + threadIdx.x;
    if (idx >= 2049 * 2049) return;
    const int j = idx / 2049;
    const int i = idx - j * 2049;
    const float gx = (float)(i - 1024) * (1.0f / 1024.0f);
    const float gy = (float)(j - 1024) * (1.0f / 1024.0f);
    const float f = sample_level<1024>(l1, gx, gy)
                  + sample_level< 512>(l2, gx, gy)
                  + sample_level< 256>(l3, gx, gy)
                  + sample_level< 128>(l4, gx, gy);
    const unsigned short h = __half_as_ushort(__float2half(f));
    const bool iL = (i < 2048), iR = (i > 0);
    const bool jT = (j < 2048), jB = (j > 0);
    if (iL & jT) Qs[((size_t)(j * 2048 + i) << 2) + 0] = h;
    if (iR & jT) Qs[((size_t)(j * 2048 + i - 1) << 2) + 1] = h;
    if (iL & jB) Qs[((size_t)((j - 1) * 2048 + i) << 2) + 2] = h;
    if (iR & jB) Qs[((size_t)((j - 1) * 2048 + i - 1) << 2) + 3] = h;
}

__global__ __launch_bounds__(256) void texture_super_kernel(
    const float2* __restrict__ x,
    const uint2* __restrict__ Q,    // 2048^2 quads of 4 fp16
    float* __restrict__ out)
{
    const int p = blockIdx.x * 256 + threadIdx.x;
    float2 g = x[p];
    float iu = g.x * 2048.0f;       // u in [0,1) -> iu in [0,2048)
    float iv = g.y * 2048.0f;
    float fu = floorf(iu), fv = floorf(iv);
    int i0 = min(max((int)fu, 0), 2047);
    int j0 = min(max((int)fv, 0), 2047);
    float wx = iu - fu, wy = iv - fv;
    uint2 q = Q[((size_t)j0 << 11) + i0];
    float v00 = __half2float(__ushort_as_half((unsigned short)(q.x & 0xffffu)));
    float v10 = __half2float(__ushort_as_half((unsigned short)(q.x >> 16)));
    float v01 = __half2float(__ushort_as_half((unsigned short)(q.y & 0xffffu)));
    float v11 = __half2float(__ushort_as_half((unsigned short)(q.y >> 16)));
    float r0 = fmaf(wx, v10 - v00, v00);
    float r1 = fmaf(wx, v11 - v01, v01);
    float y  = fmaf(wy, r1 - r0, r0);
    const int b   = p >> 20;
    const int rem = p & ((1 << 20) - 1);
    float* o = out + ((size_t)(b * 3) << 20) + rem;
    o[0]               = y;
    o[(size_t)1 << 20] = y;
    o[(size_t)2 << 20] = y;
}

// ---------- round-2 fallback: per-level bf16 quads --------------------------
__device__ __forceinline__ unsigned bf16_rne(float f) {
    unsigned u = __float_as_uint(f);
    return (u + 0x7fffu + ((u >> 16) & 1u)) >> 16;
}

template <int N>
__global__ __launch_bounds__(256) void pack_kernel(const float* __restrict__ t,
                                                   uint2* __restrict__ q) {
    const int idx = blockIdx.x * 256 + threadIdx.x;
    constexpr int NP1 = N + 1;
    if (idx >= NP1 * NP1) return;
    const int ey = idx / NP1;
    const int ex = idx - ey * NP1;
    const int y0 = ey - 1, x0 = ex - 1;
    const bool yv0 = (unsigned)y0 < (unsigned)N;
    const bool yv1 = (unsigned)(y0 + 1) < (unsigned)N;
    const bool xv0 = (unsigned)x0 < (unsigned)N;
    const bool xv1 = (unsigned)(x0 + 1) < (unsigned)N;
    const float v00 = (yv0 & xv0) ? t[y0 * N + x0] : 0.0f;
    const float v10 = (yv0 & xv1) ? t[y0 * N + x0 + 1] : 0.0f;
    const float v01 = (yv1 & xv0) ? t[(y0 + 1) * N + x0] : 0.0f;
    const float v11 = (yv1 & xv1) ? t[(y0 + 1) * N + x0 + 1] : 0.0f;
    uint2 r;
    r.x = bf16_rne(v00) | (bf16_rne(v10) << 16);
    r.y = bf16_rne(v01) | (bf16_rne(v11) << 16);
    q[idx] = r;
}

template <int N>
__device__ __forceinline__ float sample_packed(const uint2* __restrict__ q,
                                               float u, float v) {
    float ix = fmaf(u, (float)N, -0.5f);
    float iy = fmaf(v, (float)N, -0.5f);
    float x0f = floorf(ix), y0f = floorf(iy);
    float wx1 = ix - x0f, wy1 = iy - y0f;
    int ex = min(max((int)x0f + 1, 0), N);
    int ey = min(max((int)y0f + 1, 0), N);
    uint2 p = q[ey * (N + 1) + ex];
    float v00 = __uint_as_float(p.x << 16);
    float v10 = __uint_as_float(p.x & 0xffff0000u);
    float v01 = __uint_as_float(p.y << 16);
    float v11 = __uint_as_float(p.y & 0xffff0000u);
    float wx0 = 1.0f - wx1, wy0 = 1.0f - wy1;
    float r0 = fmaf(wx0, v00, wx1 * v10);
    float r1 = fmaf(wx0, v01, wx1 * v11);
    return fmaf(wy0, r0, wy1 * r1);
}

__global__ __launch_bounds__(256) void texture_quad_kernel(
    const float2* __restrict__ x,
    const uint2* __restrict__ q1, const uint2* __restrict__ q2,
    const uint2* __restrict__ q3, const uint2* __restrict__ q4,
    float* __restrict__ out)
{
    const int p = blockIdx.x * 256 + threadIdx.x;
    float2 g = x[p];
    float y = sample_packed<1024>(q1, g.x, g.y)
            + sample_packed< 512>(q2, g.x, g.y)
            + sample_packed< 256>(q3, g.x, g.y)
            + sample_packed< 128>(q4, g.x, g.y);
    const int b = p >> 20;
    const int rem = p & ((1 << 20) - 1);
    float* o = out + ((size_t)(b * 3) << 20) + rem;
    o[0] = y; o[(size_t)1 << 20] = y; o[(size_t)2 << 20] = y;
}

// ---------- round-1 fallback: direct f32 sampling ---------------------------
__global__ __launch_bounds__(256) void texture_pyramid_kernel(
    const float2* __restrict__ x,
    const float* __restrict__ l1, const float* __restrict__ l2,
    const float* __restrict__ l3, const float* __restrict__ l4,
    float* __restrict__ out)
{
    const int p = blockIdx.x * 256 + threadIdx.x;
    float2 g = x[p];
    float gx = g.x * 2.0f - 1.0f;
    float gy = g.y * 2.0f - 1.0f;
    float y = sample_level<1024>(l1, gx, gy) + sample_level<512>(l2, gx, gy)
            + sample_level<256>(l3, gx, gy) + sample_level<128>(l4, gx, gy);
    const int b = p >> 20;
    const int rem = p & ((1 << 20) - 1);
    float* o = out + ((size_t)(b * 3) << 20) + rem;
    o[0] = y; o[(size_t)1 << 20] = y; o[(size_t)2 << 20] = y;
}
// ----------------------------------------------------------------------------

extern "C" void kernel_launch(void* const* d_in, const int* in_sizes, int n_in,
                              void* d_out, int out_size, void* d_ws, size_t ws_size,
                              hipStream_t stream) {
    const float2* x  = (const float2*)d_in[0];
    const float*  l1 = (const float*)d_in[1];
    const float*  l2 = (const float*)d_in[2];
    const float*  l3 = (const float*)d_in[3];
    const float*  l4 = (const float*)d_in[4];
    float* out = (float*)d_out;

    const int total_pixels = 16 * 1024 * 1024;
    const int block = 256;
    const int grid = total_pixels / block;

    const size_t need_super = 2048ull * 2048ull * 8ull;   // 33.6 MB

    const size_t n1 = 1025ull * 1025ull, n2 = 513ull * 513ull,
                 n3 = 257ull * 257ull,   n4 = 129ull * 129ull;
    const size_t need_quads = (n1 + n2 + n3 + n4) * sizeof(uint2);  // 11.2 MB

    if (ws_size >= need_super) {
        unsigned short* Qs = (unsigned short*)d_ws;
        const int nodes = 2049 * 2049;
        build_nodes_kernel<<<(nodes + 255) / 256, 256, 0, stream>>>(
            l1, l2, l3, l4, Qs);
        texture_super_kernel<<<grid, block, 0, stream>>>(
            x, (const uint2*)d_ws, out);
    } else if (ws_size >= need_quads) {
        uint2* q1 = (uint2*)d_ws;
        uint2* q2 = q1 + n1;
        uint2* q3 = q2 + n2;
        uint2* q4 = q3 + n3;
        pack_kernel<1024><<<(int)((n1 + 255) / 256), 256, 0, stream>>>(l1, q1);
        pack_kernel< 512><<<(int)((n2 + 255) / 256), 256, 0, stream>>>(l2, q2);
        pack_kernel< 256><<<(int)((n3 + 255) / 256), 256, 0, stream>>>(l3, q3);
        pack_kernel< 128><<<(int)((n4 + 255) / 256), 256, 0, stream>>>(l4, q4);
        texture_quad_kernel<<<grid, block, 0, stream>>>(x, q1, q2, q3, q4, out);
    } else {
        texture_pyramid_kernel<<<grid, block, 0, stream>>>(x, l1, l2, l3, l4, out);
    }
}

// Round 5
// 348.136 us; speedup vs baseline: 2.6615x; 1.0100x over previous
//
#include <hip/hip_runtime.h>
#include <hip/hip_fp16.h>

// Texture pyramid bilinear sampling. All 3 output channels are the SAME
// pyramid1 sum -> compute once, write 3 planes.
//
// Supertexture approach (round 3): the 4-level sum is piecewise bilinear on a
// single 2048^2 cell grid -> precompute node values at 2049^2 grid points,
// pack each cell's 4 corners as fp16x4 (uint2), main kernel does ONE
// scattered 8B load per pixel.
//
// Round-4: attack the L2-miss fill path (33.6MB texture vs 4MB per-XCD L2).
//  - 4 pixels/thread: 4 independent gathers in flight (latency hiding),
//    16B-vectorized x loads and out stores.
//  - nontemporal hints on streaming x/out (clang ext_vector types — the
//    builtin rejects HIP_vector_type).

typedef float  f32x4 __attribute__((ext_vector_type(4)));
typedef unsigned int u32x2 __attribute__((ext_vector_type(2)));

// ---------- exact f32 sampler (zero padding), used by build + fallback ------
template <int N>
__device__ __forceinline__ float sample_level(const float* __restrict__ t,
                                              float gx, float gy) {
    float ix = ((gx + 1.0f) * (float)N - 1.0f) * 0.5f;
    float iy = ((gy + 1.0f) * (float)N - 1.0f) * 0.5f;
    float x0f = floorf(ix), y0f = floorf(iy);
    float wx1 = ix - x0f, wy1 = iy - y0f;
    float wx0 = 1.0f - wx1, wy0 = 1.0f - wy1;
    int x0 = (int)x0f, y0 = (int)y0f;
    bool vx0 = (x0 >= 0) & (x0 <= N - 1);
    bool vx1 = (x0 >= -1) & (x0 <= N - 2);
    bool vy0 = (y0 >= 0) & (y0 <= N - 1);
    bool vy1 = (y0 >= -1) & (y0 <= N - 2);
    int x0c = min(max(x0, 0), N - 1), x1c = min(max(x0 + 1, 0), N - 1);
    int y0c = min(max(y0, 0), N - 1), y1c = min(max(y0 + 1, 0), N - 1);
    const float* r0 = t + y0c * N;
    const float* r1 = t + y1c * N;
    float v00 = (vx0 & vy0) ? r0[x0c] : 0.0f;
    float v10 = (vx1 & vy0) ? r0[x1c] : 0.0f;
    float v01 = (vx0 & vy1) ? r1[x0c] : 0.0f;
    float v11 = (vx1 & vy1) ? r1[x1c] : 0.0f;
    return wx0 * wy0 * v00 + wx1 * wy0 * v10 + wx0 * wy1 * v01 + wx1 * wy1 * v11;
}

// ---------- supertexture build ----------------------------------------------
// Node (i,j), i,j in [0,2048]: gx=(i-1024)/1024 exact.
// Quad entry (j0,i0): slots {n(i0,j0), n(i0+1,j0), n(i0,j0+1), n(i0+1,j0+1)}.
__global__ __launch_bounds__(256) void build_nodes_kernel(
    const float* __restrict__ l1, const float* __restrict__ l2,
    const float* __restrict__ l3, const float* __restrict__ l4,
    unsigned short* __restrict__ Qs)
{
    const int idx = blockIdx.x * 256 + threadIdx.x;
    if (idx >= 2049 * 2049) return;
    const int j = idx / 2049;
    const int i = idx - j * 2049;
    const float gx = (float)(i - 1024) * (1.0f / 1024.0f);
    const float gy = (float)(j - 1024) * (1.0f / 1024.0f);
    const float f = sample_level<1024>(l1, gx, gy)
                  + sample_level< 512>(l2, gx, gy)
                  + sample_level< 256>(l3, gx, gy)
                  + sample_level< 128>(l4, gx, gy);
    const unsigned short h = __half_as_ushort(__float2half(f));
    const bool iL = (i < 2048), iR = (i > 0);
    const bool jT = (j < 2048), jB = (j > 0);
    if (iL & jT) Qs[((size_t)(j * 2048 + i) << 2) + 0] = h;
    if (iR & jT) Qs[((size_t)(j * 2048 + i - 1) << 2) + 1] = h;
    if (iL & jB) Qs[((size_t)((j - 1) * 2048 + i) << 2) + 2] = h;
    if (iR & jB) Qs[((size_t)((j - 1) * 2048 + i - 1) << 2) + 3] = h;
}

// ---------- main: 4 pixels per thread ---------------------------------------
__device__ __forceinline__ float sample_super(const uint2* __restrict__ Q,
                                              float u, float v) {
    float iu = u * 2048.0f;
    float iv = v * 2048.0f;
    float fu = floorf(iu), fv = floorf(iv);
    int i0 = min(max((int)fu, 0), 2047);
    int j0 = min(max((int)fv, 0), 2047);
    float wx = iu - fu, wy = iv - fv;
    uint2 q = Q[((size_t)j0 << 11) + i0];
    float v00 = __half2float(__ushort_as_half((unsigned short)(q.x & 0xffffu)));
    float v10 = __half2float(__ushort_as_half((unsigned short)(q.x >> 16)));
    float v01 = __half2float(__ushort_as_half((unsigned short)(q.y & 0xffffu)));
    float v11 = __half2float(__ushort_as_half((unsigned short)(q.y >> 16)));
    float r0 = fmaf(wx, v10 - v00, v00);
    float r1 = fmaf(wx, v11 - v01, v01);
    return fmaf(wy, r1 - r0, r0);
}

__global__ __launch_bounds__(256) void texture_super4_kernel(
    const f32x4* __restrict__ x,    // 2 pixels (gx,gy pairs) per f32x4
    const uint2* __restrict__ Q,    // 2048^2 quads of 4 fp16
    float* __restrict__ out)
{
    const int t = blockIdx.x * 256 + threadIdx.x;   // 4 pixels per thread
    const int p = t << 2;

    f32x4 c01 = __builtin_nontemporal_load(&x[(size_t)t * 2]);
    f32x4 c23 = __builtin_nontemporal_load(&x[(size_t)t * 2 + 1]);

    float y0 = sample_super(Q, c01.x, c01.y);
    float y1 = sample_super(Q, c01.z, c01.w);
    float y2 = sample_super(Q, c23.x, c23.y);
    float y3 = sample_super(Q, c23.z, c23.w);

    const int b   = p >> 20;                 // HO*WO = 2^20 (divisible by 4)
    const int rem = p & ((1 << 20) - 1);
    float* o = out + ((size_t)(b * 3) << 20) + rem;
    f32x4 v = { y0, y1, y2, y3 };
    __builtin_nontemporal_store(v, (f32x4*)(o));
    __builtin_nontemporal_store(v, (f32x4*)(o + ((size_t)1 << 20)));
    __builtin_nontemporal_store(v, (f32x4*)(o + ((size_t)2 << 20)));
}

// ---------- fallback: direct f32 sampling (only if d_ws too small) ----------
__global__ __launch_bounds__(256) void texture_pyramid_kernel(
    const float2* __restrict__ x,
    const float* __restrict__ l1, const float* __restrict__ l2,
    const float* __restrict__ l3, const float* __restrict__ l4,
    float* __restrict__ out)
{
    const int p = blockIdx.x * 256 + threadIdx.x;
    float2 g = x[p];
    float gx = g.x * 2.0f - 1.0f;
    float gy = g.y * 2.0f - 1.0f;
    float y = sample_level<1024>(l1, gx, gy) + sample_level<512>(l2, gx, gy)
            + sample_level<256>(l3, gx, gy) + sample_level<128>(l4, gx, gy);
    const int b = p >> 20;
    const int rem = p & ((1 << 20) - 1);
    float* o = out + ((size_t)(b * 3) << 20) + rem;
    o[0] = y; o[(size_t)1 << 20] = y; o[(size_t)2 << 20] = y;
}
// ----------------------------------------------------------------------------

extern "C" void kernel_launch(void* const* d_in, const int* in_sizes, int n_in,
                              void* d_out, int out_size, void* d_ws, size_t ws_size,
                              hipStream_t stream) {
    const float*  l1 = (const float*)d_in[1];
    const float*  l2 = (const float*)d_in[2];
    const float*  l3 = (const float*)d_in[3];
    const float*  l4 = (const float*)d_in[4];
    float* out = (float*)d_out;

    const int total_pixels = 16 * 1024 * 1024;   // 2^24
    const size_t need_super = 2048ull * 2048ull * 8ull;   // 33.6 MB

    if (ws_size >= need_super) {
        unsigned short* Qs = (unsigned short*)d_ws;
        const int nodes = 2049 * 2049;
        build_nodes_kernel<<<(nodes + 255) / 256, 256, 0, stream>>>(
            l1, l2, l3, l4, Qs);
        const int threads = total_pixels / 4;     // 4 px/thread
        texture_super4_kernel<<<threads / 256, 256, 0, stream>>>(
            (const f32x4*)d_in[0], (const uint2*)d_ws, out);
    } else {
        texture_pyramid_kernel<<<total_pixels / 256, 256, 0, stream>>>(
            (const float2*)d_in[0], l1, l2, l3, l4, out);
    }
}